// Round 1
// baseline (451.131 us; speedup 1.0000x reference)
//
#include <hip/hip_runtime.h>
#include <hip/hip_bf16.h>

typedef __attribute__((ext_vector_type(8))) short bf16x8;   // 8 bf16 = 4 VGPR
typedef __attribute__((ext_vector_type(4))) float f32x4;

#define GLOBAL_AS __attribute__((address_space(1)))
#define LDS_AS __attribute__((address_space(3)))

static __device__ __forceinline__ void async16(void* lds, const void* g) {
  // 16B global -> LDS direct (wave-uniform LDS base + lane*16)
  __builtin_amdgcn_global_load_lds((const GLOBAL_AS void*)g, (LDS_AS void*)lds, 16, 0, 0);
}

static __device__ __forceinline__ short f2bf(float f) {  // RNE
  union { float f; unsigned u; } v; v.f = f;
  unsigned r = v.u + 0x7fffu + ((v.u >> 16) & 1u);
  return (short)(r >> 16);
}

#define S_LEN 2048
#define D_MODEL 1024
#define H_DIM 64
#define M_TOT 8192

// ---------------- convert fp32->bf16 + mask bit-pack ----------------
__global__ __launch_bounds__(256) void convert_pack(
    const float* __restrict__ q, const float* __restrict__ k, const float* __restrict__ v,
    const float* __restrict__ wq, const float* __restrict__ wk, const float* __restrict__ wv,
    const float* __restrict__ wo, const int* __restrict__ mask,
    short* __restrict__ qb, short* __restrict__ kb, short* __restrict__ vb,
    short* __restrict__ wqb, short* __restrict__ wkb, short* __restrict__ wvb,
    short* __restrict__ wob, unsigned long long* __restrict__ mbits)
{
  int bid = blockIdx.x;
  if (bid < 14336) {                     // 14336*256*8 = 29360128 bf16 elems exactly
    long long e = ((long long)bid * 256 + threadIdx.x) * 8;
    const float* src; short* dst; long long off;
    if      (e < 8388608)  { src = q;  dst = qb;  off = e; }
    else if (e < 16777216) { src = k;  dst = kb;  off = e - 8388608; }
    else if (e < 25165824) { src = v;  dst = vb;  off = e - 16777216; }
    else if (e < 26214400) { src = wq; dst = wqb; off = e - 25165824; }
    else if (e < 27262976) { src = wk; dst = wkb; off = e - 26214400; }
    else if (e < 28311552) { src = wv; dst = wvb; off = e - 27262976; }
    else                   { src = wo; dst = wob; off = e - 28311552; }
    float4 f0 = *(const float4*)(src + off);
    float4 f1 = *(const float4*)(src + off + 4);
    bf16x8 r;
    r[0]=f2bf(f0.x); r[1]=f2bf(f0.y); r[2]=f2bf(f0.z); r[3]=f2bf(f0.w);
    r[4]=f2bf(f1.x); r[5]=f2bf(f1.y); r[6]=f2bf(f1.z); r[7]=f2bf(f1.w);
    *(bf16x8*)(dst + off) = r;
  } else {                               // mask: 2048 rows x 32 u64 words, 1 wave/word
    int wid = (bid - 14336) * 4 + (threadIdx.x >> 6);
    int lane = threadIdx.x & 63;
    int mv = mask[(long long)wid * 64 + lane];
    unsigned long long bal = __ballot(mv != 0);
    if (lane == 0) mbits[wid] = bal;
  }
}

// ---------------- bf16 GEMM, C[M,N] = A[M,K] * Bt[N,K]^T (+bias)*scale ----------------
// 128x128 tile, BK=32, 4 waves (2x2), 16x16x32 MFMA, global_load_lds staging with
// XOR chunk-swizzle (chunk ^= row&3) applied on the *global source* (linear LDS dest)
// and on the ds_read side — both-sides involution (rule #21).
struct GB { const short* A; const short* Bt; void* C; const float* bias; float scale; };

template<int OUT_BF16>
__global__ __launch_bounds__(256) void gemm_bt(GB g0, GB g1, GB g2)
{
  GB g = (blockIdx.z == 0) ? g0 : ((blockIdx.z == 1) ? g1 : g2);
  const int K = 1024, N = 1024;
  __shared__ __align__(16) short As[128 * 32];
  __shared__ __align__(16) short Bs[128 * 32];
  int tid = threadIdx.x;
  int lane = tid & 63, wave = tid >> 6;
  int wr = wave >> 1, wc = wave & 1;
  long long m0 = (long long)blockIdx.y * 128;
  int n0 = blockIdx.x * 128;
  const short* Ab = g.A + m0 * K;
  const short* Bb = g.Bt + (long long)n0 * K;

  f32x4 acc[4][4];
#pragma unroll
  for (int m = 0; m < 4; ++m)
#pragma unroll
    for (int n = 0; n < 4; ++n) { f32x4 z = {0.f,0.f,0.f,0.f}; acc[m][n] = z; }

  for (int k0 = 0; k0 < K; k0 += 32) {
    __syncthreads();                      // prev tile reads done
#pragma unroll
    for (int it = 0; it < 2; ++it) {      // A tile 128x32: 512 16B slots
      int f = it * 256 + tid;
      int row = f >> 2, cs = f & 3, c = cs ^ (row & 3);
      async16(&As[(it * 256 + (tid & 192)) * 8], Ab + (long long)row * K + k0 + c * 8);
    }
#pragma unroll
    for (int it = 0; it < 2; ++it) {
      int f = it * 256 + tid;
      int row = f >> 2, cs = f & 3, c = cs ^ (row & 3);
      async16(&Bs[(it * 256 + (tid & 192)) * 8], Bb + (long long)row * K + k0 + c * 8);
    }
    __syncthreads();                      // staging visible (vmcnt drained)

    bf16x8 af[4], bfr[4];
#pragma unroll
    for (int m = 0; m < 4; ++m) {
      int r = wr * 64 + m * 16 + (lane & 15);
      int cs = (lane >> 4) ^ (r & 3);
      af[m] = *(const bf16x8*)&As[r * 32 + cs * 8];
    }
#pragma unroll
    for (int n = 0; n < 4; ++n) {
      int r = wc * 64 + n * 16 + (lane & 15);
      int cs = (lane >> 4) ^ (r & 3);
      bfr[n] = *(const bf16x8*)&Bs[r * 32 + cs * 8];
    }
#pragma unroll
    for (int m = 0; m < 4; ++m)
#pragma unroll
      for (int n = 0; n < 4; ++n)
        acc[m][n] = __builtin_amdgcn_mfma_f32_16x16x32_bf16(af[m], bfr[n], acc[m][n], 0, 0, 0);
  }

  // epilogue: C layout col = lane&15, row = (lane>>4)*4 + j  [m89/m91]
  float bv[4];
#pragma unroll
  for (int n = 0; n < 4; ++n) bv[n] = g.bias[n0 + wc * 64 + n * 16 + (lane & 15)];
  long long crow0 = m0 + wr * 64 + ((lane >> 4) * 4);
  int ccol0 = n0 + wc * 64 + (lane & 15);
#pragma unroll
  for (int m = 0; m < 4; ++m)
#pragma unroll
    for (int n = 0; n < 4; ++n)
#pragma unroll
      for (int j = 0; j < 4; ++j) {
        long long row = crow0 + m * 16 + j;
        int col = ccol0 + n * 16;
        float val = (acc[m][n][j] + bv[n]) * g.scale;
        if (OUT_BF16) ((short*)g.C)[row * N + col] = f2bf(val);
        else          ((float*)g.C)[row * N + col] = val;
      }
}

// ---------------- flash attention ----------------
// grid (32 qtiles, 64 bh), 256 thr = 4 waves; wave w owns q rows q0+16w..+16.
// Q prescaled by 1/8 in the projection epilogue.
__global__ __launch_bounds__(256) void attn_fwd(
    const short* __restrict__ Qb, const short* __restrict__ Kb, const short* __restrict__ Vb,
    const unsigned long long* __restrict__ mbits, short* __restrict__ Xb)
{
  int bh = blockIdx.y;
  int b = bh >> 4, h = bh & 15;
  int q0 = blockIdx.x * 64;
  int tid = threadIdx.x, lane = tid & 63, wave = tid >> 6;
  long long base = (long long)b * S_LEN * D_MODEL + h * H_DIM;
  const short* Qh = Qb + base;
  const short* Kh = Kb + base;
  const short* Vh = Vb + base;

  __shared__ __align__(16) short Ks[64 * 64];      // swizzled (chunk ^= row&7)
  __shared__ __align__(16) short Vt[64][72];       // V^T, padded stride 72
  __shared__ __align__(16) short Ps[4][16][72];    // per-wave P, padded

  bf16x8 qf[2];
  {
    int qr = q0 + wave * 16 + (lane & 15);
#pragma unroll
    for (int kc = 0; kc < 2; ++kc)
      qf[kc] = *(const bf16x8*)&Qh[(long long)qr * D_MODEL + kc * 32 + (lane >> 4) * 8];
  }

  f32x4 accO[4];
#pragma unroll
  for (int n = 0; n < 4; ++n) { f32x4 z = {0.f,0.f,0.f,0.f}; accO[n] = z; }
  float mrow[4] = {-1e30f, -1e30f, -1e30f, -1e30f};
  float lrow[4] = {0.f, 0.f, 0.f, 0.f};
  int qg0 = q0 + wave * 16 + ((lane >> 4) * 4);    // C-layout row base for this lane

  for (int t = 0; t < 32; ++t) {
    int k0 = t * 64;
    __syncthreads();                               // prev tile LDS reads done
#pragma unroll
    for (int it = 0; it < 2; ++it) {               // K tile 64x64, swizzled
      int f = it * 256 + tid;
      int row = f >> 3, cs = f & 7, c = cs ^ (row & 7);
      async16(&Ks[(it * 256 + (tid & 192)) * 8], Kh + (long long)(k0 + row) * D_MODEL + c * 8);
    }
#pragma unroll
    for (int it = 0; it < 2; ++it) {               // V tile -> transposed LDS
      int f = it * 256 + tid;
      int key = f >> 3, dc = (f & 7) * 8;
      bf16x8 vv = *(const bf16x8*)&Vh[(long long)(k0 + key) * D_MODEL + dc];
#pragma unroll
      for (int j = 0; j < 8; ++j) Vt[dc + j][key] = vv[j];
    }
    unsigned long long mw[4];
#pragma unroll
    for (int j = 0; j < 4; ++j) mw[j] = mbits[(long long)(qg0 + j) * 32 + t];
    __syncthreads();

    // scores S[16q x 64k] = Q Kt^T
    f32x4 sc[4];
#pragma unroll
    for (int n = 0; n < 4; ++n) {
      f32x4 s = {0.f,0.f,0.f,0.f};
      int r = n * 16 + (lane & 15);
#pragma unroll
      for (int kc = 0; kc < 2; ++kc) {
        int cs = (kc * 4 + (lane >> 4)) ^ (r & 7);
        bf16x8 kf = *(const bf16x8*)&Ks[r * 64 + cs * 8];
        s = __builtin_amdgcn_mfma_f32_16x16x32_bf16(qf[kc], kf, s, 0, 0, 0);
      }
      sc[n] = s;
    }

    // mask + wave-parallel online softmax (rows live in 16-lane groups)
    float tmax[4] = {-1e30f,-1e30f,-1e30f,-1e30f};
    int kcol = lane & 15;
#pragma unroll
    for (int n = 0; n < 4; ++n)
#pragma unroll
      for (int j = 0; j < 4; ++j) {
        float sv = sc[n][j];
        sv = ((mw[j] >> (n * 16 + kcol)) & 1ull) ? sv : -1e30f;
        sc[n][j] = sv;
        tmax[j] = fmaxf(tmax[j], sv);
      }
#pragma unroll
    for (int d = 1; d < 16; d <<= 1)
#pragma unroll
      for (int j = 0; j < 4; ++j) tmax[j] = fmaxf(tmax[j], __shfl_xor(tmax[j], d));

    float osc[4], psum[4];
#pragma unroll
    for (int j = 0; j < 4; ++j) {
      float mnew = fmaxf(mrow[j], tmax[j]);
      osc[j] = __expf(mrow[j] - mnew);
      mrow[j] = mnew;
      psum[j] = 0.f;
    }
#pragma unroll
    for (int n = 0; n < 4; ++n)
#pragma unroll
      for (int j = 0; j < 4; ++j) {
        float p = __expf(sc[n][j] - mrow[j]);
        sc[n][j] = p;
        psum[j] += p;
      }
#pragma unroll
    for (int d = 1; d < 16; d <<= 1)
#pragma unroll
      for (int j = 0; j < 4; ++j) psum[j] += __shfl_xor(psum[j], d);
#pragma unroll
    for (int j = 0; j < 4; ++j) lrow[j] = lrow[j] * osc[j] + psum[j];
#pragma unroll
    for (int n = 0; n < 4; ++n)
#pragma unroll
      for (int j = 0; j < 4; ++j) accO[n][j] *= osc[j];

    // P -> LDS (C layout -> A layout), wave-local so no barrier needed
#pragma unroll
    for (int n = 0; n < 4; ++n)
#pragma unroll
      for (int j = 0; j < 4; ++j)
        Ps[wave][(lane >> 4) * 4 + j][n * 16 + kcol] = f2bf(sc[n][j]);

    bf16x8 pf[2];
#pragma unroll
    for (int kc = 0; kc < 2; ++kc)
      pf[kc] = *(const bf16x8*)&Ps[wave][lane & 15][kc * 32 + (lane >> 4) * 8];
#pragma unroll
    for (int n = 0; n < 4; ++n)
#pragma unroll
      for (int kc = 0; kc < 2; ++kc) {
        bf16x8 vf = *(const bf16x8*)&Vt[n * 16 + (lane & 15)][kc * 32 + (lane >> 4) * 8];
        accO[n] = __builtin_amdgcn_mfma_f32_16x16x32_bf16(pf[kc], vf, accO[n], 0, 0, 0);
      }
  }

  // x[b*S+q][h*64+dh] bf16
#pragma unroll
  for (int n = 0; n < 4; ++n)
#pragma unroll
    for (int j = 0; j < 4; ++j) {
      float o = accO[n][j] / lrow[j];
      long long row = (long long)b * S_LEN + (qg0 + j);
      Xb[row * D_MODEL + h * H_DIM + n * 16 + (lane & 15)] = f2bf(o);
    }
}

// ---------------- launch ----------------
extern "C" void kernel_launch(void* const* d_in, const int* in_sizes, int n_in,
                              void* d_out, int out_size, void* d_ws, size_t ws_size,
                              hipStream_t stream) {
  const float* q   = (const float*)d_in[0];
  const float* k   = (const float*)d_in[1];
  const float* v   = (const float*)d_in[2];
  const int*  mask = (const int*)d_in[3];
  const float* Wq  = (const float*)d_in[4];
  const float* bq  = (const float*)d_in[5];
  const float* Wk  = (const float*)d_in[6];
  const float* bk  = (const float*)d_in[7];
  const float* Wv  = (const float*)d_in[8];
  const float* bv  = (const float*)d_in[9];
  const float* Wo  = (const float*)d_in[10];
  const float* bo  = (const float*)d_in[11];

  char* w = (char*)d_ws;
  short* qb  = (short*)(w + 0LL);
  short* kb  = (short*)(w + 16777216LL);
  short* vb  = (short*)(w + 33554432LL);
  short* wqb = (short*)(w + 50331648LL);
  short* wkb = (short*)(w + 52428800LL);
  short* wvb = (short*)(w + 54525952LL);
  short* wob = (short*)(w + 56623104LL);
  short* Qb  = (short*)(w + 58720256LL);
  short* Kb  = (short*)(w + 75497472LL);
  short* Vb  = (short*)(w + 92274688LL);
  short* Xb  = (short*)(w + 109051904LL);
  unsigned long long* mbits = (unsigned long long*)(w + 125829120LL);
  // total ws use: 126353408 bytes

  convert_pack<<<30720, 256, 0, stream>>>(q, k, v, Wq, Wk, Wv, Wo, mask,
                                          qb, kb, vb, wqb, wkb, wvb, wob, mbits);
  GB g0{qb, wqb, (void*)Qb, bq, 0.125f};   // fold 1/sqrt(64) into Q
  GB g1{kb, wkb, (void*)Kb, bk, 1.0f};
  GB g2{vb, wvb, (void*)Vb, bv, 1.0f};
  gemm_bt<1><<<dim3(8, 64, 3), 256, 0, stream>>>(g0, g1, g2);
  attn_fwd<<<dim3(32, 64), 256, 0, stream>>>(Qb, Kb, Vb, mbits, Xb);
  GB go{Xb, wob, d_out, bo, 1.0f};
  gemm_bt<0><<<dim3(8, 64, 1), 256, 0, stream>>>(go, go, go);
}

// Round 2
// 337.922 us; speedup vs baseline: 1.3350x; 1.3350x over previous
//
#include <hip/hip_runtime.h>
#include <hip/hip_bf16.h>

typedef __attribute__((ext_vector_type(8))) short bf16x8;   // 8 bf16 = 4 VGPR
typedef __attribute__((ext_vector_type(4))) short bf16x4;   // 4 bf16 = 2 VGPR
typedef __attribute__((ext_vector_type(4))) float f32x4;

#define GLOBAL_AS __attribute__((address_space(1)))
#define LDS_AS __attribute__((address_space(3)))

static __device__ __forceinline__ void async16(void* lds, const void* g) {
  // 16B global -> LDS direct (wave-uniform LDS base + lane*16)
  __builtin_amdgcn_global_load_lds((const GLOBAL_AS void*)g, (LDS_AS void*)lds, 16, 0, 0);
}

static __device__ __forceinline__ short f2bf(float f) {  // RNE
  union { float f; unsigned u; } v; v.f = f;
  unsigned r = v.u + 0x7fffu + ((v.u >> 16) & 1u);
  return (short)(r >> 16);
}

#define S_LEN 2048
#define D_MODEL 1024
#define H_DIM 64
#define M_TOT 8192
#define QSCALE 0.18033688011112042f   /* 0.125 * log2(e): scores in log2 domain */

// ---------------- convert fp32->bf16 + mask bit-pack ----------------
__global__ __launch_bounds__(256) void convert_pack(
    const float* __restrict__ q, const float* __restrict__ k, const float* __restrict__ v,
    const float* __restrict__ wq, const float* __restrict__ wk, const float* __restrict__ wv,
    const float* __restrict__ wo, const int* __restrict__ mask,
    short* __restrict__ qb, short* __restrict__ kb, short* __restrict__ vb,
    short* __restrict__ wqb, short* __restrict__ wkb, short* __restrict__ wvb,
    short* __restrict__ wob, unsigned long long* __restrict__ mbits)
{
  int bid = blockIdx.x;
  if (bid < 14336) {                     // 14336*256*8 = 29360128 bf16 elems exactly
    long long e = ((long long)bid * 256 + threadIdx.x) * 8;
    const float* src; short* dst; long long off;
    if      (e < 8388608)  { src = q;  dst = qb;  off = e; }
    else if (e < 16777216) { src = k;  dst = kb;  off = e - 8388608; }
    else if (e < 25165824) { src = v;  dst = vb;  off = e - 16777216; }
    else if (e < 26214400) { src = wq; dst = wqb; off = e - 25165824; }
    else if (e < 27262976) { src = wk; dst = wkb; off = e - 26214400; }
    else if (e < 28311552) { src = wv; dst = wvb; off = e - 27262976; }
    else                   { src = wo; dst = wob; off = e - 28311552; }
    float4 f0 = *(const float4*)(src + off);
    float4 f1 = *(const float4*)(src + off + 4);
    bf16x8 r;
    r[0]=f2bf(f0.x); r[1]=f2bf(f0.y); r[2]=f2bf(f0.z); r[3]=f2bf(f0.w);
    r[4]=f2bf(f1.x); r[5]=f2bf(f1.y); r[6]=f2bf(f1.z); r[7]=f2bf(f1.w);
    *(bf16x8*)(dst + off) = r;
  } else {                               // mask: 2048 rows x 32 u64 words, 1 wave/word
    int wid = (bid - 14336) * 4 + (threadIdx.x >> 6);
    int lane = threadIdx.x & 63;
    int mv = mask[(long long)wid * 64 + lane];
    unsigned long long bal = __ballot(mv != 0);
    if (lane == 0) mbits[wid] = bal;
  }
}

// ---------------- bf16 GEMM, C[M,N] = A[M,K] * Bt[N,K]^T, (acc+bias)*scale ----------------
// 128x128 tile, BK=32, 4 waves (2x2), 16x16x32 MFMA, global_load_lds staging with
// XOR chunk-swizzle on the global source (linear LDS dest) + same XOR on ds_read.
// BIAS_ROW=1: bias indexed by output row (used for the transposed V projection).
struct GB { const short* A; const short* Bt; void* C; const float* bias; float scale; int N; };

template<int OUT_BF16, int BIAS_ROW>
__global__ __launch_bounds__(256) void gemm_bt(GB g0, GB g1, GB g2)
{
  GB g = (blockIdx.z == 0) ? g0 : ((blockIdx.z == 1) ? g1 : g2);
  const int K = 1024;
  const int N = g.N;
  __shared__ __align__(16) short As[128 * 32];
  __shared__ __align__(16) short Bs[128 * 32];
  int tid = threadIdx.x;
  int lane = tid & 63, wave = tid >> 6;
  int wr = wave >> 1, wc = wave & 1;
  long long m0 = (long long)blockIdx.y * 128;
  int n0 = blockIdx.x * 128;
  const short* Ab = g.A + m0 * K;
  const short* Bb = g.Bt + (long long)n0 * K;

  f32x4 acc[4][4];
#pragma unroll
  for (int m = 0; m < 4; ++m)
#pragma unroll
    for (int n = 0; n < 4; ++n) { f32x4 z = {0.f,0.f,0.f,0.f}; acc[m][n] = z; }

  for (int k0 = 0; k0 < K; k0 += 32) {
    __syncthreads();                      // prev tile reads done
#pragma unroll
    for (int it = 0; it < 2; ++it) {      // A tile 128x32: 512 16B slots
      int f = it * 256 + tid;
      int row = f >> 2, cs = f & 3, c = cs ^ (row & 3);
      async16(&As[(it * 256 + (tid & 192)) * 8], Ab + (long long)row * K + k0 + c * 8);
    }
#pragma unroll
    for (int it = 0; it < 2; ++it) {
      int f = it * 256 + tid;
      int row = f >> 2, cs = f & 3, c = cs ^ (row & 3);
      async16(&Bs[(it * 256 + (tid & 192)) * 8], Bb + (long long)row * K + k0 + c * 8);
    }
    __syncthreads();                      // staging visible (vmcnt drained)

    bf16x8 af[4], bfr[4];
#pragma unroll
    for (int m = 0; m < 4; ++m) {
      int r = wr * 64 + m * 16 + (lane & 15);
      int cs = (lane >> 4) ^ (r & 3);
      af[m] = *(const bf16x8*)&As[r * 32 + cs * 8];
    }
#pragma unroll
    for (int n = 0; n < 4; ++n) {
      int r = wc * 64 + n * 16 + (lane & 15);
      int cs = (lane >> 4) ^ (r & 3);
      bfr[n] = *(const bf16x8*)&Bs[r * 32 + cs * 8];
    }
#pragma unroll
    for (int m = 0; m < 4; ++m)
#pragma unroll
      for (int n = 0; n < 4; ++n)
        acc[m][n] = __builtin_amdgcn_mfma_f32_16x16x32_bf16(af[m], bfr[n], acc[m][n], 0, 0, 0);
  }

  // epilogue: C layout col = lane&15, row = (lane>>4)*4 + j  [m89/m91]
  float bcol[4];
  if (!BIAS_ROW) {
#pragma unroll
    for (int n = 0; n < 4; ++n) bcol[n] = g.bias[n0 + wc * 64 + n * 16 + (lane & 15)];
  }
  long long crow0 = m0 + wr * 64 + ((lane >> 4) * 4);
  int ccol0 = n0 + wc * 64 + (lane & 15);
#pragma unroll
  for (int m = 0; m < 4; ++m) {
    float brow[4];
    if (BIAS_ROW) {
#pragma unroll
      for (int j = 0; j < 4; ++j) brow[j] = g.bias[crow0 + m * 16 + j];
    }
#pragma unroll
    for (int n = 0; n < 4; ++n)
#pragma unroll
      for (int j = 0; j < 4; ++j) {
        long long row = crow0 + m * 16 + j;
        int col = ccol0 + n * 16;
        float val = (acc[m][n][j] + (BIAS_ROW ? brow[j] : bcol[n])) * g.scale;
        if (OUT_BF16) ((short*)g.C)[row * N + col] = f2bf(val);
        else          ((float*)g.C)[row * N + col] = val;
      }
  }
}

// ---------------- flash attention (swapped QK^T, vectorized P path, dbuf staging) ---------
// grid (32 qtiles, 64 bh), 256 thr = 4 waves; wave w owns q rows q0+16w..+16.
// Q prescaled by (1/8)*log2(e) in the projection epilogue -> softmax in exp2 domain.
// Per-lane ownership: c=lane&15 = q-row (softmax stats), output rows = 4g+j (C layout).
__global__ __launch_bounds__(256) void attn_fwd(
    const short* __restrict__ Qb, const short* __restrict__ Kb, const short* __restrict__ Vtg,
    const unsigned long long* __restrict__ mbits, short* __restrict__ Xb)
{
  int bh = blockIdx.y;
  int b = bh >> 4, h = bh & 15;
  int q0 = blockIdx.x * 64;
  int tid = threadIdx.x, lane = tid & 63, wave = tid >> 6;
  int c = lane & 15, g = lane >> 4;
  const short* Qh = Qb + (long long)b * S_LEN * D_MODEL + h * H_DIM;
  const short* Kh = Kb + (long long)b * S_LEN * D_MODEL + h * H_DIM;
  const short* Vh = Vtg + (long long)(h * H_DIM) * M_TOT + b * S_LEN;  // V^T rows = d

  __shared__ __align__(16) short Ks[2][64 * 64];   // K rows, chunk-swizzled ^(row&7)
  __shared__ __align__(16) short Vs[2][64 * 64];   // V^T rows (d), chunk-swizzled ^(d&7)
  __shared__ __align__(16) short Ps[4][16 * 64];   // per-wave P, chunk-swizzled ^(q&7)

  int qr = q0 + wave * 16 + c;
  bf16x8 qf[2];
#pragma unroll
  for (int kc = 0; kc < 2; ++kc)
    qf[kc] = *(const bf16x8*)&Qh[(long long)qr * D_MODEL + kc * 32 + g * 8];

  f32x4 accO[4];
#pragma unroll
  for (int nd = 0; nd < 4; ++nd) { f32x4 z = {0.f,0.f,0.f,0.f}; accO[nd] = z; }
  float mrow = -1e30f, lrow = 0.f;

#define STAGE(t, buf) do {                                                            \
    int k0_ = (t) * 64;                                                               \
    _Pragma("unroll") for (int it = 0; it < 2; ++it) {                                \
      int f = it * 256 + tid; int row = f >> 3, cs = f & 7;                           \
      async16(&Ks[buf][(it * 256 + (tid & 192)) * 8],                                 \
              Kh + (long long)(k0_ + row) * D_MODEL + ((cs ^ (row & 7)) * 8));        \
    }                                                                                 \
    _Pragma("unroll") for (int it = 0; it < 2; ++it) {                                \
      int f = it * 256 + tid; int d = f >> 3, cs = f & 7;                             \
      async16(&Vs[buf][(it * 256 + (tid & 192)) * 8],                                 \
              Vh + (long long)d * M_TOT + k0_ + ((cs ^ (d & 7)) * 8));                \
    }                                                                                 \
  } while (0)

  STAGE(0, 0);
  unsigned long long mw = mbits[(long long)qr * 32];
  __syncthreads();

  for (int t = 0; t < 32; ++t) {
    int cur = t & 1;
    if (t < 31) STAGE(t + 1, cur ^ 1);                   // prefetch next tile
    unsigned long long mw_next = (t < 31) ? mbits[(long long)qr * 32 + t + 1] : 0ull;

    // S^T tile: sc[n][j] = S[q=c][k = n*16 + 4g + j]   (mfma operands swapped)
    f32x4 sc[4];
#pragma unroll
    for (int n = 0; n < 4; ++n) {
      f32x4 s = {0.f, 0.f, 0.f, 0.f};
      int r = n * 16 + c;
#pragma unroll
      for (int kc = 0; kc < 2; ++kc) {
        bf16x8 kf = *(const bf16x8*)&Ks[cur][r * 64 + (((kc * 4 + g) ^ (r & 7)) * 8)];
        s = __builtin_amdgcn_mfma_f32_16x16x32_bf16(kf, qf[kc], s, 0, 0, 0);
      }
      sc[n] = s;
    }

    // mask + online softmax (one q-row per lane; stats shared across g via 2 shfl)
    float tmax = -1e30f;
#pragma unroll
    for (int n = 0; n < 4; ++n)
#pragma unroll
      for (int j = 0; j < 4; ++j) {
        float sv = sc[n][j];
        sv = ((mw >> (n * 16 + 4 * g + j)) & 1ull) ? sv : -1e30f;
        sc[n][j] = sv;
        tmax = fmaxf(tmax, sv);
      }
    tmax = fmaxf(tmax, __shfl_xor(tmax, 16));
    tmax = fmaxf(tmax, __shfl_xor(tmax, 32));
    float mnew = fmaxf(mrow, tmax);
    float osc = exp2f(mrow - mnew);
    mrow = mnew;
    float psum = 0.f;
#pragma unroll
    for (int n = 0; n < 4; ++n)
#pragma unroll
      for (int j = 0; j < 4; ++j) {
        float pv = exp2f(sc[n][j] - mnew);
        sc[n][j] = pv;
        psum += pv;
      }
    psum += __shfl_xor(psum, 16);
    psum += __shfl_xor(psum, 32);
    lrow = lrow * osc + psum;

    // rescale accO: factor lives at lane with c == output row (4g+j)
    float oj[4];
#pragma unroll
    for (int j = 0; j < 4; ++j) oj[j] = __shfl(osc, (lane & 48) | (4 * g + j));
#pragma unroll
    for (int nd = 0; nd < 4; ++nd)
#pragma unroll
      for (int j = 0; j < 4; ++j) accO[nd][j] *= oj[j];

    // P -> LDS: 4 consecutive k per lane -> one ds_write_b64 per n (swizzled)
#pragma unroll
    for (int n = 0; n < 4; ++n) {
      bf16x4 pk;
      pk[0] = f2bf(sc[n][0]); pk[1] = f2bf(sc[n][1]);
      pk[2] = f2bf(sc[n][2]); pk[3] = f2bf(sc[n][3]);
      int chs = (2 * n + (g >> 1)) ^ (c & 7);
      *(bf16x4*)&Ps[wave][c * 64 + chs * 8 + (g & 1) * 4] = pk;
    }

    // PV: P as A-frag (row q=c), V^T as B-frag (col d), both vector b128 reads
#pragma unroll
    for (int kc = 0; kc < 2; ++kc) {
      bf16x8 pf = *(const bf16x8*)&Ps[wave][c * 64 + (((kc * 4 + g) ^ (c & 7)) * 8)];
#pragma unroll
      for (int nd = 0; nd < 4; ++nd) {
        int dr = nd * 16 + c;
        bf16x8 vf = *(const bf16x8*)&Vs[cur][dr * 64 + (((kc * 4 + g) ^ (dr & 7)) * 8)];
        accO[nd] = __builtin_amdgcn_mfma_f32_16x16x32_bf16(pf, vf, accO[nd], 0, 0, 0);
      }
    }
    mw = mw_next;
    __syncthreads();   // drains vmcnt: tile t+1 staged; Ks/Vs[cur] reads done for overwrite
  }

  // epilogue: accO[nd][j] = O[q=4g+j][d=nd*16+c]; lrow lives at lane c==q
  float lr[4];
#pragma unroll
  for (int j = 0; j < 4; ++j) lr[j] = __shfl(lrow, (lane & 48) | (4 * g + j));
#pragma unroll
  for (int nd = 0; nd < 4; ++nd)
#pragma unroll
    for (int j = 0; j < 4; ++j) {
      float o = accO[nd][j] / lr[j];
      long long row = (long long)b * S_LEN + q0 + wave * 16 + 4 * g + j;
      Xb[row * D_MODEL + h * H_DIM + nd * 16 + c] = f2bf(o);
    }
#undef STAGE
}

// ---------------- launch ----------------
extern "C" void kernel_launch(void* const* d_in, const int* in_sizes, int n_in,
                              void* d_out, int out_size, void* d_ws, size_t ws_size,
                              hipStream_t stream) {
  const float* q   = (const float*)d_in[0];
  const float* k   = (const float*)d_in[1];
  const float* v   = (const float*)d_in[2];
  const int*  mask = (const int*)d_in[3];
  const float* Wq  = (const float*)d_in[4];
  const float* bq  = (const float*)d_in[5];
  const float* Wk  = (const float*)d_in[6];
  const float* bk  = (const float*)d_in[7];
  const float* Wv  = (const float*)d_in[8];
  const float* bv  = (const float*)d_in[9];
  const float* Wo  = (const float*)d_in[10];
  const float* bo  = (const float*)d_in[11];

  char* w = (char*)d_ws;
  short* qb  = (short*)(w + 0LL);
  short* kb  = (short*)(w + 16777216LL);
  short* vb  = (short*)(w + 33554432LL);
  short* wqb = (short*)(w + 50331648LL);
  short* wkb = (short*)(w + 52428800LL);
  short* wvb = (short*)(w + 54525952LL);
  short* wob = (short*)(w + 56623104LL);
  short* Qb  = (short*)(w + 58720256LL);
  short* Kb  = (short*)(w + 75497472LL);
  short* Vtg = (short*)(w + 92274688LL);   // V^T: [1024 d][8192 tokens]
  short* Xb  = (short*)(w + 109051904LL);
  unsigned long long* mbits = (unsigned long long*)(w + 125829120LL);
  // total ws use: 126353408 bytes

  convert_pack<<<30720, 256, 0, stream>>>(q, k, v, Wq, Wk, Wv, Wo, mask,
                                          qb, kb, vb, wqb, wkb, wvb, wob, mbits);
  // Q,K projections (col-bias). Q folds (1/8)*log2(e).
  GB gq{qb, wqb, (void*)Qb, bq, QSCALE, 1024};
  GB gk{kb, wkb, (void*)Kb, bk, 1.0f, 1024};
  gemm_bt<1, 0><<<dim3(8, 64, 2), 256, 0, stream>>>(gq, gk, gk);
  // V projection TRANSPOSED: C[d][token] = Wv[d][:] . v[token][:] + bv[d] (row-bias)
  GB gv{wvb, vb, (void*)Vtg, bv, 1.0f, 8192};
  gemm_bt<1, 1><<<dim3(64, 8, 1), 256, 0, stream>>>(gv, gv, gv);

  attn_fwd<<<dim3(32, 64), 256, 0, stream>>>(Qb, Kb, Vtg, mbits, Xb);

  GB go{Xb, wob, d_out, bo, 1.0f, 1024};
  gemm_bt<0, 0><<<dim3(8, 64, 1), 256, 0, stream>>>(go, go, go);
}

// Round 3
// 316.504 us; speedup vs baseline: 1.4254x; 1.0677x over previous
//
#include <hip/hip_runtime.h>
#include <hip/hip_bf16.h>

typedef __attribute__((ext_vector_type(8))) short bf16x8;   // 8 bf16 = 4 VGPR
typedef __attribute__((ext_vector_type(4))) short bf16x4;   // 4 bf16 = 2 VGPR
typedef __attribute__((ext_vector_type(4))) float f32x4;

#define GLOBAL_AS __attribute__((address_space(1)))
#define LDS_AS __attribute__((address_space(3)))

static __device__ __forceinline__ void async16(void* lds, const void* g) {
  // 16B global -> LDS direct (wave-uniform LDS base + lane*16)
  __builtin_amdgcn_global_load_lds((const GLOBAL_AS void*)g, (LDS_AS void*)lds, 16, 0, 0);
}

static __device__ __forceinline__ short f2bf(float f) {  // RNE (manual, used off hot path)
  union { float f; unsigned u; } v; v.f = f;
  unsigned r = v.u + 0x7fffu + ((v.u >> 16) & 1u);
  return (short)(r >> 16);
}

static __device__ __forceinline__ short f2bf_fast(float f) {  // native cvt (RNE)
  union { __hip_bfloat16 h; short s; } u; u.h = __float2bfloat16(f); return u.s;
}

#define S_LEN 2048
#define D_MODEL 1024
#define H_DIM 64
#define M_TOT 8192
#define QSCALE 0.18033688011112042f   /* 0.125 * log2(e): scores in log2 domain */

// ---------------- convert fp32->bf16 + mask bit-pack ----------------
__global__ __launch_bounds__(256) void convert_pack(
    const float* __restrict__ q, const float* __restrict__ k, const float* __restrict__ v,
    const float* __restrict__ wq, const float* __restrict__ wk, const float* __restrict__ wv,
    const float* __restrict__ wo, const int* __restrict__ mask,
    short* __restrict__ qb, short* __restrict__ kb, short* __restrict__ vb,
    short* __restrict__ wqb, short* __restrict__ wkb, short* __restrict__ wvb,
    short* __restrict__ wob, unsigned long long* __restrict__ mbits)
{
  int bid = blockIdx.x;
  if (bid < 14336) {                     // 14336*256*8 = 29360128 bf16 elems exactly
    long long e = ((long long)bid * 256 + threadIdx.x) * 8;
    const float* src; short* dst; long long off;
    if      (e < 8388608)  { src = q;  dst = qb;  off = e; }
    else if (e < 16777216) { src = k;  dst = kb;  off = e - 8388608; }
    else if (e < 25165824) { src = v;  dst = vb;  off = e - 16777216; }
    else if (e < 26214400) { src = wq; dst = wqb; off = e - 25165824; }
    else if (e < 27262976) { src = wk; dst = wkb; off = e - 26214400; }
    else if (e < 28311552) { src = wv; dst = wvb; off = e - 27262976; }
    else                   { src = wo; dst = wob; off = e - 28311552; }
    float4 f0 = *(const float4*)(src + off);
    float4 f1 = *(const float4*)(src + off + 4);
    bf16x8 r;
    r[0]=f2bf(f0.x); r[1]=f2bf(f0.y); r[2]=f2bf(f0.z); r[3]=f2bf(f0.w);
    r[4]=f2bf(f1.x); r[5]=f2bf(f1.y); r[6]=f2bf(f1.z); r[7]=f2bf(f1.w);
    *(bf16x8*)(dst + off) = r;
  } else {                               // mask: 2048 rows x 32 u64 words, 1 wave/word
    int wid = (bid - 14336) * 4 + (threadIdx.x >> 6);
    int lane = threadIdx.x & 63;
    int mv = mask[(long long)wid * 64 + lane];
    unsigned long long bal = __ballot(mv != 0);
    if (lane == 0) mbits[wid] = bal;
  }
}

// ---------------- bf16 GEMM, C[M,N] = A[M,K] * Bt[N,K]^T, (acc+bias)*scale ----------------
struct GB { const short* A; const short* Bt; void* C; const float* bias; float scale; int N; };

template<int OUT_BF16, int BIAS_ROW>
__global__ __launch_bounds__(256) void gemm_bt(GB g0, GB g1, GB g2)
{
  GB g = (blockIdx.z == 0) ? g0 : ((blockIdx.z == 1) ? g1 : g2);
  const int K = 1024;
  const int N = g.N;
  __shared__ __align__(16) short As[128 * 32];
  __shared__ __align__(16) short Bs[128 * 32];
  int tid = threadIdx.x;
  int lane = tid & 63, wave = tid >> 6;
  int wr = wave >> 1, wc = wave & 1;
  long long m0 = (long long)blockIdx.y * 128;
  int n0 = blockIdx.x * 128;
  const short* Ab = g.A + m0 * K;
  const short* Bb = g.Bt + (long long)n0 * K;

  f32x4 acc[4][4];
#pragma unroll
  for (int m = 0; m < 4; ++m)
#pragma unroll
    for (int n = 0; n < 4; ++n) { f32x4 z = {0.f,0.f,0.f,0.f}; acc[m][n] = z; }

  for (int k0 = 0; k0 < K; k0 += 32) {
    __syncthreads();                      // prev tile reads done
#pragma unroll
    for (int it = 0; it < 2; ++it) {      // A tile 128x32: 512 16B slots
      int f = it * 256 + tid;
      int row = f >> 2, cs = f & 3, c = cs ^ (row & 3);
      async16(&As[(it * 256 + (tid & 192)) * 8], Ab + (long long)row * K + k0 + c * 8);
    }
#pragma unroll
    for (int it = 0; it < 2; ++it) {
      int f = it * 256 + tid;
      int row = f >> 2, cs = f & 3, c = cs ^ (row & 3);
      async16(&Bs[(it * 256 + (tid & 192)) * 8], Bb + (long long)row * K + k0 + c * 8);
    }
    __syncthreads();                      // staging visible (vmcnt drained)

    bf16x8 af[4], bfr[4];
#pragma unroll
    for (int m = 0; m < 4; ++m) {
      int r = wr * 64 + m * 16 + (lane & 15);
      int cs = (lane >> 4) ^ (r & 3);
      af[m] = *(const bf16x8*)&As[r * 32 + cs * 8];
    }
#pragma unroll
    for (int n = 0; n < 4; ++n) {
      int r = wc * 64 + n * 16 + (lane & 15);
      int cs = (lane >> 4) ^ (r & 3);
      bfr[n] = *(const bf16x8*)&Bs[r * 32 + cs * 8];
    }
#pragma unroll
    for (int m = 0; m < 4; ++m)
#pragma unroll
      for (int n = 0; n < 4; ++n)
        acc[m][n] = __builtin_amdgcn_mfma_f32_16x16x32_bf16(af[m], bfr[n], acc[m][n], 0, 0, 0);
  }

  // epilogue: C layout col = lane&15, row = (lane>>4)*4 + j  [m89/m91]
  float bcol[4];
  if (!BIAS_ROW) {
#pragma unroll
    for (int n = 0; n < 4; ++n) bcol[n] = g.bias[n0 + wc * 64 + n * 16 + (lane & 15)];
  }
  long long crow0 = m0 + wr * 64 + ((lane >> 4) * 4);
  int ccol0 = n0 + wc * 64 + (lane & 15);
#pragma unroll
  for (int m = 0; m < 4; ++m) {
    float brow[4];
    if (BIAS_ROW) {
#pragma unroll
      for (int j = 0; j < 4; ++j) brow[j] = g.bias[crow0 + m * 16 + j];
    }
#pragma unroll
    for (int n = 0; n < 4; ++n)
#pragma unroll
      for (int j = 0; j < 4; ++j) {
        long long row = crow0 + m * 16 + j;
        int col = ccol0 + n * 16;
        float val = (acc[m][n][j] + (BIAS_ROW ? brow[j] : bcol[n])) * g.scale;
        if (OUT_BF16) ((short*)g.C)[row * N + col] = f2bf(val);
        else          ((float*)g.C)[row * N + col] = val;
      }
  }
}

// ---------------- flash attention (swapped QK^T, VALU-dieted softmax) ----------------
// grid (32 qtiles, 64 bh), 256 thr = 4 waves; wave w owns q rows q0+16w..+16.
// Q prescaled by (1/8)*log2(e) -> softmax in exp2 domain.
// Per-lane: c=lane&15 = q-row (softmax stats), g=lane>>4 covers k 4-chunks.
__global__ __launch_bounds__(256) void attn_fwd(
    const short* __restrict__ Qb, const short* __restrict__ Kb, const short* __restrict__ Vtg,
    const unsigned long long* __restrict__ mbits, short* __restrict__ Xb)
{
  int bh = blockIdx.y;
  int b = bh >> 4, h = bh & 15;
  int q0 = blockIdx.x * 64;
  int tid = threadIdx.x, lane = tid & 63, wave = tid >> 6;
  int c = lane & 15, g = lane >> 4;
  const short* Qh = Qb + (long long)b * S_LEN * D_MODEL + h * H_DIM;
  const short* Kh = Kb + (long long)b * S_LEN * D_MODEL + h * H_DIM;
  const short* Vh = Vtg + (long long)(h * H_DIM) * M_TOT + b * S_LEN;  // V^T rows = d

  __shared__ __align__(16) short Ks[2][64 * 64];   // K rows, chunk-swizzled ^(row&7)
  __shared__ __align__(16) short Vs[2][64 * 64];   // V^T rows (d), chunk-swizzled ^(d&7)
  __shared__ __align__(16) short Ps[4][16 * 64];   // per-wave P, chunk-swizzled ^(q&7)

  int qr = q0 + wave * 16 + c;
  bf16x8 qf[2];
#pragma unroll
  for (int kc = 0; kc < 2; ++kc)
    qf[kc] = *(const bf16x8*)&Qh[(long long)qr * D_MODEL + kc * 32 + g * 8];

  f32x4 accO[4];
#pragma unroll
  for (int nd = 0; nd < 4; ++nd) { f32x4 z = {0.f,0.f,0.f,0.f}; accO[nd] = z; }
  float mrow = -1e30f, lrow = 0.f;
  int shn[4];
#pragma unroll
  for (int n = 0; n < 4; ++n) shn[n] = n * 16 + 4 * g;   // hoisted mask shift amounts

#define STAGE(t, buf) do {                                                            \
    int k0_ = (t) * 64;                                                               \
    _Pragma("unroll") for (int it = 0; it < 2; ++it) {                                \
      int f = it * 256 + tid; int row = f >> 3, cs = f & 7;                           \
      async16(&Ks[buf][(it * 256 + (tid & 192)) * 8],                                 \
              Kh + (long long)(k0_ + row) * D_MODEL + ((cs ^ (row & 7)) * 8));        \
    }                                                                                 \
    _Pragma("unroll") for (int it = 0; it < 2; ++it) {                                \
      int f = it * 256 + tid; int d = f >> 3, cs = f & 7;                             \
      async16(&Vs[buf][(it * 256 + (tid & 192)) * 8],                                 \
              Vh + (long long)d * M_TOT + k0_ + ((cs ^ (d & 7)) * 8));                \
    }                                                                                 \
  } while (0)

  STAGE(0, 0);
  unsigned long long mw = mbits[(long long)qr * 32];
  __syncthreads();

  for (int t = 0; t < 32; ++t) {
    int cur = t & 1;
    if (t < 31) STAGE(t + 1, cur ^ 1);                   // prefetch next tile
    unsigned long long mw_next = (t < 31) ? mbits[(long long)qr * 32 + t + 1] : 0ull;

    // S^T tile: sc[n][j] = S[q=c][k = n*16 + 4g + j]   (mfma operands swapped)
    f32x4 sc[4];
#pragma unroll
    for (int n = 0; n < 4; ++n) {
      f32x4 s = {0.f, 0.f, 0.f, 0.f};
      int r = n * 16 + c;
#pragma unroll
      for (int kc = 0; kc < 2; ++kc) {
        bf16x8 kf = *(const bf16x8*)&Ks[cur][r * 64 + (((kc * 4 + g) ^ (r & 7)) * 8)];
        s = __builtin_amdgcn_mfma_f32_16x16x32_bf16(kf, qf[kc], s, 0, 0, 0);
      }
      sc[n] = s;
    }

    // raw-score max (mask applied post-exp; any upper bound is valid for softmax)
    float t0 = fmaxf(fmaxf(sc[0][0], sc[0][1]), sc[0][2]);
    float t1 = fmaxf(fmaxf(sc[0][3], sc[1][0]), sc[1][1]);
    float t2 = fmaxf(fmaxf(sc[1][2], sc[1][3]), sc[2][0]);
    float t3 = fmaxf(fmaxf(sc[2][1], sc[2][2]), sc[2][3]);
    float t4 = fmaxf(fmaxf(sc[3][0], sc[3][1]), sc[3][2]);
    float tmax = fmaxf(fmaxf(fmaxf(t0, t1), fmaxf(t2, t3)), fmaxf(t4, sc[3][3]));
    tmax = fmaxf(tmax, __shfl_xor(tmax, 16));
    tmax = fmaxf(tmax, __shfl_xor(tmax, 32));

    // T13 defer-rescale: skip when every row's tile max is within +4 (log2) of mrow
    if (__any(tmax > mrow + 4.0f)) {
      float mnew = fmaxf(mrow, tmax);
      float osc = exp2f(mrow - mnew);
      mrow = mnew;
      lrow *= osc;
      float oj0 = __shfl(osc, (lane & 48) | (4 * g + 0));
      float oj1 = __shfl(osc, (lane & 48) | (4 * g + 1));
      float oj2 = __shfl(osc, (lane & 48) | (4 * g + 2));
      float oj3 = __shfl(osc, (lane & 48) | (4 * g + 3));
      f32x4 ojv = {oj0, oj1, oj2, oj3};
#pragma unroll
      for (int nd = 0; nd < 4; ++nd) accO[nd] *= ojv;
    }

    // exp2 + mask (sign-extend AND: masked p -> exactly 0)
#pragma unroll
    for (int n = 0; n < 4; ++n) {
      unsigned mn = (unsigned)(mw >> shn[n]);
#pragma unroll
      for (int j = 0; j < 4; ++j) {
        float pv = exp2f(sc[n][j] - mrow);
        int sm = __builtin_amdgcn_sbfe(mn, j, 1);   // 0 or -1
        union { float f; unsigned u; } pu; pu.f = pv;
        pu.u &= (unsigned)sm;
        sc[n][j] = pu.f;
      }
    }
    f32x4 pa = sc[0] + sc[1];
    f32x4 pb = sc[2] + sc[3];
    f32x4 pt = pa + pb;
    float psum = (pt[0] + pt[1]) + (pt[2] + pt[3]);
    psum += __shfl_xor(psum, 16);
    psum += __shfl_xor(psum, 32);
    lrow += psum;

    // P -> LDS: 4 consecutive k per lane -> one ds_write_b64 per n (swizzled)
#pragma unroll
    for (int n = 0; n < 4; ++n) {
      bf16x4 pk;
      pk[0] = f2bf_fast(sc[n][0]); pk[1] = f2bf_fast(sc[n][1]);
      pk[2] = f2bf_fast(sc[n][2]); pk[3] = f2bf_fast(sc[n][3]);
      int chs = (2 * n + (g >> 1)) ^ (c & 7);
      *(bf16x4*)&Ps[wave][c * 64 + chs * 8 + (g & 1) * 4] = pk;
    }

    // PV: P as A-frag (row q=c), V^T as B-frag (col d), both vector b128 reads
#pragma unroll
    for (int kc = 0; kc < 2; ++kc) {
      bf16x8 pf = *(const bf16x8*)&Ps[wave][c * 64 + (((kc * 4 + g) ^ (c & 7)) * 8)];
#pragma unroll
      for (int nd = 0; nd < 4; ++nd) {
        int dr = nd * 16 + c;
        bf16x8 vf = *(const bf16x8*)&Vs[cur][dr * 64 + (((kc * 4 + g) ^ (dr & 7)) * 8)];
        accO[nd] = __builtin_amdgcn_mfma_f32_16x16x32_bf16(pf, vf, accO[nd], 0, 0, 0);
      }
    }
    mw = mw_next;
    __syncthreads();   // drains vmcnt: tile t+1 staged; Ks/Vs[cur] reads done for overwrite
  }

  // epilogue: accO[nd][j] = O[q=4g+j][d=nd*16+c]; lrow lives at lane c==q
  float lr[4];
#pragma unroll
  for (int j = 0; j < 4; ++j) lr[j] = __shfl(lrow, (lane & 48) | (4 * g + j));
#pragma unroll
  for (int nd = 0; nd < 4; ++nd)
#pragma unroll
    for (int j = 0; j < 4; ++j) {
      float o = accO[nd][j] / lr[j];
      long long row = (long long)b * S_LEN + q0 + wave * 16 + 4 * g + j;
      Xb[row * D_MODEL + h * H_DIM + nd * 16 + c] = f2bf(o);
    }
#undef STAGE
}

// ---------------- launch ----------------
extern "C" void kernel_launch(void* const* d_in, const int* in_sizes, int n_in,
                              void* d_out, int out_size, void* d_ws, size_t ws_size,
                              hipStream_t stream) {
  const float* q   = (const float*)d_in[0];
  const float* k   = (const float*)d_in[1];
  const float* v   = (const float*)d_in[2];
  const int*  mask = (const int*)d_in[3];
  const float* Wq  = (const float*)d_in[4];
  const float* bq  = (const float*)d_in[5];
  const float* Wk  = (const float*)d_in[6];
  const float* bk  = (const float*)d_in[7];
  const float* Wv  = (const float*)d_in[8];
  const float* bv  = (const float*)d_in[9];
  const float* Wo  = (const float*)d_in[10];
  const float* bo  = (const float*)d_in[11];

  char* w = (char*)d_ws;
  short* qb  = (short*)(w + 0LL);
  short* kb  = (short*)(w + 16777216LL);
  short* vb  = (short*)(w + 33554432LL);
  short* wqb = (short*)(w + 50331648LL);
  short* wkb = (short*)(w + 52428800LL);
  short* wvb = (short*)(w + 54525952LL);
  short* wob = (short*)(w + 56623104LL);
  short* Qb  = (short*)(w + 58720256LL);
  short* Kb  = (short*)(w + 75497472LL);
  short* Vtg = (short*)(w + 92274688LL);   // V^T: [1024 d][8192 tokens]
  short* Xb  = (short*)(w + 109051904LL);
  unsigned long long* mbits = (unsigned long long*)(w + 125829120LL);
  // total ws use: 126353408 bytes

  convert_pack<<<30720, 256, 0, stream>>>(q, k, v, Wq, Wk, Wv, Wo, mask,
                                          qb, kb, vb, wqb, wkb, wvb, wob, mbits);
  // Q,K projections (col-bias). Q folds (1/8)*log2(e).
  GB gq{qb, wqb, (void*)Qb, bq, QSCALE, 1024};
  GB gk{kb, wkb, (void*)Kb, bk, 1.0f, 1024};
  gemm_bt<1, 0><<<dim3(8, 64, 2), 256, 0, stream>>>(gq, gk, gk);
  // V projection TRANSPOSED: C[d][token] = Wv[d][:] . v[token][:] + bv[d] (row-bias)
  GB gv{wvb, vb, (void*)Vtg, bv, 1.0f, 8192};
  gemm_bt<1, 1><<<dim3(64, 8, 1), 256, 0, stream>>>(gv, gv, gv);

  attn_fwd<<<dim3(32, 64), 256, 0, stream>>>(Qb, Kb, Vtg, mbits, Xb);

  GB go{Xb, wob, d_out, bo, 1.0f, 1024};
  gemm_bt<0, 0><<<dim3(8, 64, 1), 256, 0, stream>>>(go, go, go);
}

// Round 4
// 304.108 us; speedup vs baseline: 1.4835x; 1.0408x over previous
//
#include <hip/hip_runtime.h>
#include <hip/hip_bf16.h>

typedef __attribute__((ext_vector_type(8))) short bf16x8;   // 8 bf16 = 4 VGPR
typedef __attribute__((ext_vector_type(4))) short bf16x4;   // 4 bf16 = 2 VGPR
typedef __attribute__((ext_vector_type(4))) float f32x4;

#define GLOBAL_AS __attribute__((address_space(1)))
#define LDS_AS __attribute__((address_space(3)))

static __device__ __forceinline__ void async16(void* lds, const void* g) {
  // 16B global -> LDS direct (wave-uniform LDS base + lane*16)
  __builtin_amdgcn_global_load_lds((const GLOBAL_AS void*)g, (LDS_AS void*)lds, 16, 0, 0);
}

static __device__ __forceinline__ short f2bf(float f) {  // RNE (manual, off hot path)
  union { float f; unsigned u; } v; v.f = f;
  unsigned r = v.u + 0x7fffu + ((v.u >> 16) & 1u);
  return (short)(r >> 16);
}

static __device__ __forceinline__ short f2bf_fast(float f) {  // native cvt (RNE)
  union { __hip_bfloat16 h; short s; } u; u.h = __float2bfloat16(f); return u.s;
}

#define S_LEN 2048
#define D_MODEL 1024
#define H_DIM 64
#define M_TOT 8192
#define QSCALE 0.18033688011112042f   /* 0.125 * log2(e): scores in log2 domain */

// ---------------- convert fp32->bf16 + mask bit-pack ----------------
__global__ __launch_bounds__(256) void convert_pack(
    const float* __restrict__ q, const float* __restrict__ k, const float* __restrict__ v,
    const float* __restrict__ wq, const float* __restrict__ wk, const float* __restrict__ wv,
    const float* __restrict__ wo, const int* __restrict__ mask,
    short* __restrict__ qb, short* __restrict__ kb, short* __restrict__ vb,
    short* __restrict__ wqb, short* __restrict__ wkb, short* __restrict__ wvb,
    short* __restrict__ wob, unsigned long long* __restrict__ mbits)
{
  int bid = blockIdx.x;
  if (bid < 14336) {                     // 14336*256*8 = 29360128 bf16 elems exactly
    long long e = ((long long)bid * 256 + threadIdx.x) * 8;
    const float* src; short* dst; long long off;
    if      (e < 8388608)  { src = q;  dst = qb;  off = e; }
    else if (e < 16777216) { src = k;  dst = kb;  off = e - 8388608; }
    else if (e < 25165824) { src = v;  dst = vb;  off = e - 16777216; }
    else if (e < 26214400) { src = wq; dst = wqb; off = e - 25165824; }
    else if (e < 27262976) { src = wk; dst = wkb; off = e - 26214400; }
    else if (e < 28311552) { src = wv; dst = wvb; off = e - 27262976; }
    else                   { src = wo; dst = wob; off = e - 28311552; }
    float4 f0 = *(const float4*)(src + off);
    float4 f1 = *(const float4*)(src + off + 4);
    bf16x8 r;
    r[0]=f2bf(f0.x); r[1]=f2bf(f0.y); r[2]=f2bf(f0.z); r[3]=f2bf(f0.w);
    r[4]=f2bf(f1.x); r[5]=f2bf(f1.y); r[6]=f2bf(f1.z); r[7]=f2bf(f1.w);
    *(bf16x8*)(dst + off) = r;
  } else {                               // mask: 2048 rows x 32 u64 words, 1 wave/word
    int wid = (bid - 14336) * 4 + (threadIdx.x >> 6);
    int lane = threadIdx.x & 63;
    int mv = mask[(long long)wid * 64 + lane];
    unsigned long long bal = __ballot(mv != 0);
    if (lane == 0) mbits[wid] = bal;
  }
}

// ---------------- bf16 GEMM, C[M,N] = A[M,K] * Bt[N,K]^T, (acc+bias)*scale ----------------
struct GB { const short* A; const short* Bt; void* C; const float* bias; float scale; int N; };

template<int OUT_BF16, int BIAS_ROW>
__global__ __launch_bounds__(256) void gemm_bt(GB g0, GB g1, GB g2)
{
  GB g = (blockIdx.z == 0) ? g0 : ((blockIdx.z == 1) ? g1 : g2);
  const int K = 1024;
  const int N = g.N;
  __shared__ __align__(16) short As[128 * 32];
  __shared__ __align__(16) short Bs[128 * 32];
  int tid = threadIdx.x;
  int lane = tid & 63, wave = tid >> 6;
  int wr = wave >> 1, wc = wave & 1;
  long long m0 = (long long)blockIdx.y * 128;
  int n0 = blockIdx.x * 128;
  const short* Ab = g.A + m0 * K;
  const short* Bb = g.Bt + (long long)n0 * K;

  f32x4 acc[4][4];
#pragma unroll
  for (int m = 0; m < 4; ++m)
#pragma unroll
    for (int n = 0; n < 4; ++n) { f32x4 z = {0.f,0.f,0.f,0.f}; acc[m][n] = z; }

  for (int k0 = 0; k0 < K; k0 += 32) {
    __syncthreads();                      // prev tile reads done
#pragma unroll
    for (int it = 0; it < 2; ++it) {      // A tile 128x32: 512 16B slots
      int f = it * 256 + tid;
      int row = f >> 2, cs = f & 3, c = cs ^ (row & 3);
      async16(&As[(it * 256 + (tid & 192)) * 8], Ab + (long long)row * K + k0 + c * 8);
    }
#pragma unroll
    for (int it = 0; it < 2; ++it) {
      int f = it * 256 + tid;
      int row = f >> 2, cs = f & 3, c = cs ^ (row & 3);
      async16(&Bs[(it * 256 + (tid & 192)) * 8], Bb + (long long)row * K + k0 + c * 8);
    }
    __syncthreads();                      // staging visible (vmcnt drained)

    bf16x8 af[4], bfr[4];
#pragma unroll
    for (int m = 0; m < 4; ++m) {
      int r = wr * 64 + m * 16 + (lane & 15);
      int cs = (lane >> 4) ^ (r & 3);
      af[m] = *(const bf16x8*)&As[r * 32 + cs * 8];
    }
#pragma unroll
    for (int n = 0; n < 4; ++n) {
      int r = wc * 64 + n * 16 + (lane & 15);
      int cs = (lane >> 4) ^ (r & 3);
      bfr[n] = *(const bf16x8*)&Bs[r * 32 + cs * 8];
    }
#pragma unroll
    for (int m = 0; m < 4; ++m)
#pragma unroll
      for (int n = 0; n < 4; ++n)
        acc[m][n] = __builtin_amdgcn_mfma_f32_16x16x32_bf16(af[m], bfr[n], acc[m][n], 0, 0, 0);
  }

  // epilogue: C layout col = lane&15, row = (lane>>4)*4 + j  [m89/m91]
  float bcol[4];
  if (!BIAS_ROW) {
#pragma unroll
    for (int n = 0; n < 4; ++n) bcol[n] = g.bias[n0 + wc * 64 + n * 16 + (lane & 15)];
  }
  long long crow0 = m0 + wr * 64 + ((lane >> 4) * 4);
  int ccol0 = n0 + wc * 64 + (lane & 15);
#pragma unroll
  for (int m = 0; m < 4; ++m) {
    float brow[4];
    if (BIAS_ROW) {
#pragma unroll
      for (int j = 0; j < 4; ++j) brow[j] = g.bias[crow0 + m * 16 + j];
    }
#pragma unroll
    for (int n = 0; n < 4; ++n)
#pragma unroll
      for (int j = 0; j < 4; ++j) {
        long long row = crow0 + m * 16 + j;
        int col = ccol0 + n * 16;
        float val = (acc[m][n][j] + (BIAS_ROW ? brow[j] : bcol[n])) * g.scale;
        if (OUT_BF16) ((short*)g.C)[row * N + col] = f2bf(val);
        else          ((float*)g.C)[row * N + col] = val;
      }
  }
}

// ---------------- flash attention (hoisted addressing, static dbuf unroll) ----------------
// grid (32 qtiles, 64 bh), 256 thr = 4 waves; wave w owns q rows q0+16w..+16.
// Q prescaled by (1/8)*log2(e) -> softmax in exp2 domain.
// Per-lane: c=lane&15 = q-row (softmax stats), g=lane>>4 covers k 4-chunks.
// __launch_bounds__(256,4): LDS binds occupancy to 4 blocks/CU = 4 waves/SIMD,
// so allow 128 VGPR and keep all hoisted addresses in registers.
__global__ __launch_bounds__(256, 4) void attn_fwd(
    const short* __restrict__ Qb, const short* __restrict__ Kb, const short* __restrict__ Vtg,
    const unsigned long long* __restrict__ mbits, short* __restrict__ Xb)
{
  int bh = blockIdx.y;
  int b = bh >> 4, h = bh & 15;
  int q0 = blockIdx.x * 64;
  int tid = threadIdx.x, lane = tid & 63, wave = tid >> 6;
  int c = lane & 15, g = lane >> 4;
  const short* Qh = Qb + (long long)b * S_LEN * D_MODEL + h * H_DIM;
  const short* Kh = Kb + (long long)b * S_LEN * D_MODEL + h * H_DIM;
  const short* Vh = Vtg + (long long)(h * H_DIM) * M_TOT + b * S_LEN;  // V^T rows = d

  __shared__ __align__(16) short Ks[2][64 * 64];   // K rows, chunk-swizzled ^(row&7)
  __shared__ __align__(16) short Vs[2][64 * 64];   // V^T rows (d), chunk-swizzled ^(d&7)
  __shared__ __align__(16) short Ps[4][16 * 64];   // per-wave P, chunk-swizzled ^(q&7)

  int qr = q0 + wave * 16 + c;
  bf16x8 qf[2];
#pragma unroll
  for (int kc = 0; kc < 2; ++kc)
    qf[kc] = *(const bf16x8*)&Qh[(long long)qr * D_MODEL + kc * 32 + g * 8];

  // ---- hoisted per-lane offsets (elements) ----
  const int fA = tid, fB = 256 + tid;
  const int rA = fA >> 3, rB = fB >> 3;
  const int swA = ((fA & 7) ^ (rA & 7)) * 8, swB = ((fB & 7) ^ (rB & 7)) * 8;
  const int kgA = rA * D_MODEL + swA, kgB = rB * D_MODEL + swB;   // K staging src
  const int vgA = rA * M_TOT + swA,  vgB = rB * M_TOT + swB;      // V staging src
  const int ldA = (tid & 192) * 8, ldB = (256 + (tid & 192)) * 8; // LDS dst

  int rdO[2][4];                          // K-frag & V-frag LDS offsets (same formula)
#pragma unroll
  for (int n = 0; n < 4; ++n) {
    int r = n * 16 + c;
    rdO[0][n] = r * 64 + ((g ^ (r & 7)) * 8);
    rdO[1][n] = r * 64 + (((4 + g) ^ (r & 7)) * 8);
  }
  int pfO[2];                             // P A-frag read offsets
#pragma unroll
  for (int kc = 0; kc < 2; ++kc) pfO[kc] = c * 64 + (((kc * 4 + g) ^ (c & 7)) * 8);
  int psO[4];                             // P write offsets
#pragma unroll
  for (int n = 0; n < 4; ++n) psO[n] = c * 64 + (((2 * n + (g >> 1)) ^ (c & 7)) * 8) + (g & 1) * 4;

  const unsigned long long* mpb = mbits + (long long)qr * 32;

  f32x4 accO[4];
#pragma unroll
  for (int nd = 0; nd < 4; ++nd) { f32x4 z = {0.f,0.f,0.f,0.f}; accO[nd] = z; }
  float mrow = -1e30f, lrow = 0.f;

#define STAGE(t, BUF) do {                                                   \
    const short* Kt_ = Kh + (long long)(t) * (64 * D_MODEL);                 \
    async16(&Ks[BUF][ldA], Kt_ + kgA);                                       \
    async16(&Ks[BUF][ldB], Kt_ + kgB);                                       \
    const short* Vt_ = Vh + (t) * 64;                                        \
    async16(&Vs[BUF][ldA], Vt_ + vgA);                                       \
    async16(&Vs[BUF][ldB], Vt_ + vgB);                                       \
  } while (0)

#define TILE(t, CUR) do {                                                            \
    if ((t) < 31) STAGE((t) + 1, 1 - (CUR));                                         \
    unsigned long long mw_next = ((t) < 31) ? mpb[(t) + 1] : 0ull;                   \
    const short* ksb = &Ks[CUR][0];                                                  \
    const short* vsb = &Vs[CUR][0];                                                  \
    f32x4 sc[4];                                                                     \
    _Pragma("unroll") for (int n = 0; n < 4; ++n) {                                  \
      f32x4 s = {0.f, 0.f, 0.f, 0.f};                                                \
      _Pragma("unroll") for (int kc = 0; kc < 2; ++kc) {                             \
        bf16x8 kf = *(const bf16x8*)(ksb + rdO[kc][n]);                              \
        s = __builtin_amdgcn_mfma_f32_16x16x32_bf16(kf, qf[kc], s, 0, 0, 0);         \
      }                                                                              \
      sc[n] = s;                                                                     \
    }                                                                                \
    float t0 = fmaxf(fmaxf(sc[0][0], sc[0][1]), sc[0][2]);                           \
    float t1 = fmaxf(fmaxf(sc[0][3], sc[1][0]), sc[1][1]);                           \
    float t2 = fmaxf(fmaxf(sc[1][2], sc[1][3]), sc[2][0]);                           \
    float t3 = fmaxf(fmaxf(sc[2][1], sc[2][2]), sc[2][3]);                           \
    float t4 = fmaxf(fmaxf(sc[3][0], sc[3][1]), sc[3][2]);                           \
    float tmax = fmaxf(fmaxf(fmaxf(t0, t1), fmaxf(t2, t3)), fmaxf(t4, sc[3][3]));    \
    tmax = fmaxf(tmax, __shfl_xor(tmax, 16));                                        \
    tmax = fmaxf(tmax, __shfl_xor(tmax, 32));                                        \
    if (__any(tmax > mrow + 4.0f)) {                                                 \
      float mnew = fmaxf(mrow, tmax);                                                \
      float osc = exp2f(mrow - mnew);                                                \
      mrow = mnew;                                                                   \
      lrow *= osc;                                                                   \
      float oj0 = __shfl(osc, (lane & 48) | (4 * g + 0));                            \
      float oj1 = __shfl(osc, (lane & 48) | (4 * g + 1));                            \
      float oj2 = __shfl(osc, (lane & 48) | (4 * g + 2));                            \
      float oj3 = __shfl(osc, (lane & 48) | (4 * g + 3));                            \
      f32x4 ojv = {oj0, oj1, oj2, oj3};                                              \
      _Pragma("unroll") for (int nd = 0; nd < 4; ++nd) accO[nd] *= ojv;              \
    }                                                                                \
    _Pragma("unroll") for (int n = 0; n < 4; ++n) {                                  \
      unsigned mn = (unsigned)(mw >> (n * 16 + 4 * g));                              \
      _Pragma("unroll") for (int j = 0; j < 4; ++j) {                                \
        float pv = exp2f(sc[n][j] - mrow);                                           \
        int sm = __builtin_amdgcn_sbfe(mn, j, 1);                                    \
        union { float f; unsigned u; } pu; pu.f = pv;                                \
        pu.u &= (unsigned)sm;                                                        \
        sc[n][j] = pu.f;                                                             \
      }                                                                              \
    }                                                                                \
    f32x4 pt = (sc[0] + sc[1]) + (sc[2] + sc[3]);                                    \
    float psum = (pt[0] + pt[1]) + (pt[2] + pt[3]);                                  \
    psum += __shfl_xor(psum, 16);                                                    \
    psum += __shfl_xor(psum, 32);                                                    \
    lrow += psum;                                                                    \
    _Pragma("unroll") for (int n = 0; n < 4; ++n) {                                  \
      bf16x4 pk;                                                                     \
      pk[0] = f2bf_fast(sc[n][0]); pk[1] = f2bf_fast(sc[n][1]);                      \
      pk[2] = f2bf_fast(sc[n][2]); pk[3] = f2bf_fast(sc[n][3]);                      \
      *(bf16x4*)&Ps[wave][psO[n]] = pk;                                              \
    }                                                                                \
    _Pragma("unroll") for (int kc = 0; kc < 2; ++kc) {                               \
      bf16x8 pf = *(const bf16x8*)&Ps[wave][pfO[kc]];                                \
      _Pragma("unroll") for (int nd = 0; nd < 4; ++nd) {                             \
        bf16x8 vf = *(const bf16x8*)(vsb + rdO[kc][nd]);                             \
        accO[nd] = __builtin_amdgcn_mfma_f32_16x16x32_bf16(pf, vf, accO[nd], 0, 0, 0);\
      }                                                                              \
    }                                                                                \
    mw = mw_next;                                                                    \
    __syncthreads();                                                                 \
  } while (0)

  STAGE(0, 0);
  unsigned long long mw = mpb[0];
  __syncthreads();

  for (int t = 0; t < 32; t += 2) {
    TILE(t, 0);
    TILE(t + 1, 1);
  }

  // epilogue: accO[nd][j] = O[q=4g+j][d=nd*16+c]; lrow lives at lane c==q
  float lr[4];
#pragma unroll
  for (int j = 0; j < 4; ++j) lr[j] = __shfl(lrow, (lane & 48) | (4 * g + j));
#pragma unroll
  for (int nd = 0; nd < 4; ++nd)
#pragma unroll
    for (int j = 0; j < 4; ++j) {
      float o = accO[nd][j] / lr[j];
      long long row = (long long)b * S_LEN + q0 + wave * 16 + 4 * g + j;
      Xb[row * D_MODEL + h * H_DIM + nd * 16 + c] = f2bf(o);
    }
#undef TILE
#undef STAGE
}

// ---------------- launch ----------------
extern "C" void kernel_launch(void* const* d_in, const int* in_sizes, int n_in,
                              void* d_out, int out_size, void* d_ws, size_t ws_size,
                              hipStream_t stream) {
  const float* q   = (const float*)d_in[0];
  const float* k   = (const float*)d_in[1];
  const float* v   = (const float*)d_in[2];
  const int*  mask = (const int*)d_in[3];
  const float* Wq  = (const float*)d_in[4];
  const float* bq  = (const float*)d_in[5];
  const float* Wk  = (const float*)d_in[6];
  const float* bk  = (const float*)d_in[7];
  const float* Wv  = (const float*)d_in[8];
  const float* bv  = (const float*)d_in[9];
  const float* Wo  = (const float*)d_in[10];
  const float* bo  = (const float*)d_in[11];

  char* w = (char*)d_ws;
  short* qb  = (short*)(w + 0LL);
  short* kb  = (short*)(w + 16777216LL);
  short* vb  = (short*)(w + 33554432LL);
  short* wqb = (short*)(w + 50331648LL);
  short* wkb = (short*)(w + 52428800LL);
  short* wvb = (short*)(w + 54525952LL);
  short* wob = (short*)(w + 56623104LL);
  short* Qb  = (short*)(w + 58720256LL);
  short* Kb  = (short*)(w + 75497472LL);
  short* Vtg = (short*)(w + 92274688LL);   // V^T: [1024 d][8192 tokens]
  short* Xb  = (short*)(w + 109051904LL);
  unsigned long long* mbits = (unsigned long long*)(w + 125829120LL);
  // total ws use: 126353408 bytes

  convert_pack<<<30720, 256, 0, stream>>>(q, k, v, Wq, Wk, Wv, Wo, mask,
                                          qb, kb, vb, wqb, wkb, wvb, wob, mbits);
  // Q,K projections (col-bias). Q folds (1/8)*log2(e).
  GB gq{qb, wqb, (void*)Qb, bq, QSCALE, 1024};
  GB gk{kb, wkb, (void*)Kb, bk, 1.0f, 1024};
  gemm_bt<1, 0><<<dim3(8, 64, 2), 256, 0, stream>>>(gq, gk, gk);
  // V projection TRANSPOSED: C[d][token] = Wv[d][:] . v[token][:] + bv[d] (row-bias)
  GB gv{wvb, vb, (void*)Vtg, bv, 1.0f, 8192};
  gemm_bt<1, 1><<<dim3(64, 8, 1), 256, 0, stream>>>(gv, gv, gv);

  attn_fwd<<<dim3(32, 64), 256, 0, stream>>>(Qb, Kb, Vtg, mbits, Xb);

  GB go{Xb, wob, d_out, bo, 1.0f, 1024};
  gemm_bt<0, 0><<<dim3(8, 64, 1), 256, 0, stream>>>(go, go, go);
}